// Round 1
// baseline (104.922 us; speedup 1.0000x reference)
//
#include <hip/hip_runtime.h>

// DifferentiableCensus: out[b,c,i,j] = (1/9) * sum_{3x3 window, edge-clamped}
//   sigmoid(x[nbhd] - x[center]).  Center tap == 0.5 exactly.
//
// x: (16,3,512,512) f32 -> 48 planes of 512x512.
// 1 thread = 4 contiguous pixels (float4 in/out). 128 threads cover a row.

#define CENSUS_H 512
#define CENSUS_W 512

#if __has_builtin(__builtin_amdgcn_exp2f)
#define FAST_EXP2(x) __builtin_amdgcn_exp2f(x)
#else
#define FAST_EXP2(x) exp2f(x)
#endif

#if __has_builtin(__builtin_amdgcn_rcpf)
#define FAST_RCP(x) __builtin_amdgcn_rcpf(x)
#else
#define FAST_RCP(x) (1.0f / (x))
#endif

__global__ __launch_bounds__(256) void census_kernel(const float* __restrict__ x,
                                                     float* __restrict__ out) {
    const float L2E = 1.44269504088896340736f;  // log2(e)

    int g = blockIdx.x * 256 + threadIdx.x;     // one g per 4-pixel segment
    int lane   = g & 127;                       // segment within row (128 * 4 = 512)
    int row_id = g >> 7;                        // plane*512 + i
    int i      = row_id & (CENSUS_H - 1);
    int plane  = row_id >> 9;

    size_t base = (size_t)plane * (size_t)(CENSUS_H * CENSUS_W);
    const float* rowC = x + base + (size_t)i * CENSUS_W;
    const float* rowU = x + base + (size_t)(i > 0 ? i - 1 : 0) * CENSUS_W;
    const float* rowD = x + base + (size_t)(i < CENSUS_H - 1 ? i + 1 : CENSUS_H - 1) * CENSUS_W;

    int j0 = lane << 2;
    float4 c4 = *reinterpret_cast<const float4*>(rowC + j0);
    float4 u4 = *reinterpret_cast<const float4*>(rowU + j0);
    float4 d4 = *reinterpret_cast<const float4*>(rowD + j0);

    // Halo columns, edge-clamped. For j0==0 / j0+4==W these clamp onto our own
    // first/last column, which is exactly the 'edge' pad semantics.
    int jl = (j0 > 0) ? j0 - 1 : 0;
    int jr = (j0 + 4 < CENSUS_W) ? j0 + 4 : CENSUS_W - 1;

    float m[6] = { rowC[jl], c4.x, c4.y, c4.z, c4.w, rowC[jr] };
    float u[6] = { rowU[jl], u4.x, u4.y, u4.z, u4.w, rowU[jr] };
    float d[6] = { rowD[jl], d4.x, d4.y, d4.z, d4.w, rowD[jr] };

    float o[4];
#pragma unroll
    for (int k = 0; k < 4; ++k) {
        float c   = m[k + 1];
        float cl2 = c * L2E;
        float acc = 0.5f;  // center tap: sigmoid(0)
        float taps[8] = { u[k], u[k + 1], u[k + 2],
                          m[k],           m[k + 2],
                          d[k], d[k + 1], d[k + 2] };
#pragma unroll
        for (int t = 0; t < 8; ++t) {
            // sigmoid(p - c) = 1 / (1 + exp(c - p)) ; exp(c-p) = exp2(c*L2E - p*L2E)
            float e = FAST_EXP2(fmaf(-taps[t], L2E, cl2));
            acc += FAST_RCP(1.0f + e);
        }
        o[k] = acc * (1.0f / 9.0f);
    }

    float4 ov = make_float4(o[0], o[1], o[2], o[3]);
    *reinterpret_cast<float4*>(out + base + (size_t)i * CENSUS_W + j0) = ov;
}

extern "C" void kernel_launch(void* const* d_in, const int* in_sizes, int n_in,
                              void* d_out, int out_size, void* d_ws, size_t ws_size,
                              hipStream_t stream) {
    const float* x = (const float*)d_in[0];
    float* out = (float*)d_out;

    int n = in_sizes[0];                 // 16*3*512*512 = 12582912
    int n_threads = n / 4;               // 4 pixels per thread
    int block = 256;
    int grid = (n_threads + block - 1) / block;  // 12288

    census_kernel<<<grid, block, 0, stream>>>(x, out);
}

// Round 2
// 104.309 us; speedup vs baseline: 1.0059x; 1.0059x over previous
//
#include <hip/hip_runtime.h>

// DifferentiableCensus: out[i,j] = (1/9) * sum_{3x3, edge-clamped} sigmoid(x[nb] - x[c])
// x: (16,3,512,512) f32 = 48 planes of 512x512.
//
// Key identity: sigmoid(a-b) = 1 - sigmoid(b-a) -> each unordered neighbor PAIR
// needs one transcendental evaluation, shared between the two pixels it touches.
// Thread tile: 4 cols (float4) x 8 rows, streamed row-by-row. Per output row:
//   se[5]  E-dir pairs within the row        (W tap = 1 - se[k])
//   sv[4]  S-dir pairs (cur row, next row)   (next row's N tap = 1 - sv[k])
//   sd[5]  SE-dir pairs                      (next row's NW tap = 1 - sd[k])
//   sb[5]  SW-dir pairs                      (next row's NE tap = 1 - sb[k+1])
// = 19 sigmoids/row instead of 32. Center tap = sigmoid(0) = 0.5 exactly.

#define CENSUS_H 512
#define CENSUS_W 512
#define ROWS_PER_THREAD 8

#if __has_builtin(__builtin_amdgcn_exp2f)
#define FAST_EXP2(v) __builtin_amdgcn_exp2f(v)
#else
#define FAST_EXP2(v) exp2f(v)
#endif

#if __has_builtin(__builtin_amdgcn_rcpf)
#define FAST_RCP(v) __builtin_amdgcn_rcpf(v)
#else
#define FAST_RCP(v) (1.0f / (v))
#endif

// Inputs are pre-scaled by log2(e): sigmoid(a-b) = 1/(1+exp2(b_s - a_s)).
__device__ __forceinline__ float sigdiff(float a_s, float b_s) {
    float e = FAST_EXP2(b_s - a_s);
    return FAST_RCP(1.0f + e);
}

__global__ __launch_bounds__(256) void census_kernel(const float* __restrict__ x,
                                                     float* __restrict__ out) {
    const float L2E = 1.44269504088896340736f;  // log2(e)

    int g = blockIdx.x * 256 + threadIdx.x;
    int colseg = g & 127;          // 128 segments of 4 cols = 512
    int band   = (g >> 7) & 63;    // 64 bands of 8 rows = 512
    int plane  = g >> 13;          // 48 planes

    int j0 = colseg << 2;
    int i0 = band << 3;
    int jl = (j0 > 0) ? j0 - 1 : 0;
    int jr = (j0 + 4 < CENSUS_W) ? j0 + 4 : CENSUS_W - 1;

    const float* P = x + (size_t)plane * (CENSUS_H * CENSUS_W);
    float* O = out + (size_t)plane * (CENSUS_H * CENSUS_W) + (size_t)i0 * CENSUS_W + j0;

    float cur[6], nxt[6], acc[4];

    // ---- load row (i0-1, clamped) and row i0, pre-scaled by log2(e) ----
    {
        int rm1 = (i0 > 0) ? i0 - 1 : 0;
        const float* rp = P + (size_t)rm1 * CENSUS_W;
        float4 v = *reinterpret_cast<const float4*>(rp + j0);
        cur[0] = rp[jl] * L2E; cur[1] = v.x * L2E; cur[2] = v.y * L2E;
        cur[3] = v.z * L2E;    cur[4] = v.w * L2E; cur[5] = rp[jr] * L2E;
    }
    {
        const float* rp = P + (size_t)i0 * CENSUS_W;
        float4 v = *reinterpret_cast<const float4*>(rp + j0);
        nxt[0] = rp[jl] * L2E; nxt[1] = v.x * L2E; nxt[2] = v.y * L2E;
        nxt[3] = v.z * L2E;    nxt[4] = v.w * L2E; nxt[5] = rp[jr] * L2E;
    }

    // ---- init acc for row i0: N/NW/NE taps from pairs (row i0-1, row i0) ----
    // N  = 1 - sig(nxt[k+1]-cur[k+1]); NW = 1 - sig(nxt[k+1]-cur[k]);
    // NE = 1 - sig(nxt[k+1]-cur[k+2])
#pragma unroll
    for (int k = 0; k < 4; ++k) {
        float sv = sigdiff(nxt[k + 1], cur[k + 1]);
        float sd = sigdiff(nxt[k + 1], cur[k]);
        float sb = sigdiff(nxt[k + 1], cur[k + 2]);
        acc[k] = 3.0f - sv - sd - sb;
    }
#pragma unroll
    for (int t = 0; t < 6; ++t) cur[t] = nxt[t];

    // ---- stream 8 output rows ----
#pragma unroll
    for (int r = 0; r < ROWS_PER_THREAD; ++r) {
        int row = i0 + r;
        int nrow = (row + 1 < CENSUS_H) ? row + 1 : CENSUS_H - 1;
        {
            const float* rp = P + (size_t)nrow * CENSUS_W;
            float4 v = *reinterpret_cast<const float4*>(rp + j0);
            nxt[0] = rp[jl] * L2E; nxt[1] = v.x * L2E; nxt[2] = v.y * L2E;
            nxt[3] = v.z * L2E;    nxt[4] = v.w * L2E; nxt[5] = rp[jr] * L2E;
        }

        float se[5], sv[4], sd[5], sb[5];
#pragma unroll
        for (int t = 0; t < 5; ++t) se[t] = sigdiff(cur[t + 1], cur[t]);
#pragma unroll
        for (int k = 0; k < 4; ++k) sv[k] = sigdiff(nxt[k + 1], cur[k + 1]);
#pragma unroll
        for (int t = 0; t < 5; ++t) sd[t] = sigdiff(nxt[t + 1], cur[t]);
#pragma unroll
        for (int t = 0; t < 5; ++t) sb[t] = sigdiff(nxt[t], cur[t + 1]);

        float o[4];
#pragma unroll
        for (int k = 0; k < 4; ++k) {
            // C + E + W + S + SE + SW  (N/NW/NE already in acc[k])
            float a = acc[k] + 1.5f;            // +0.5 center, +1 for the (1-se[k]) W tap
            a += se[k + 1] - se[k];             // E + (W - 1)
            a += sv[k] + sd[k + 1] + sb[k];
            o[k] = a * (1.0f / 9.0f);
            // seed next row's acc: N + NW + NE complements
            acc[k] = 3.0f - sv[k] - sd[k] - sb[k + 1];
        }
        *reinterpret_cast<float4*>(O + (size_t)r * CENSUS_W) =
            make_float4(o[0], o[1], o[2], o[3]);

#pragma unroll
        for (int t = 0; t < 6; ++t) cur[t] = nxt[t];
    }
}

extern "C" void kernel_launch(void* const* d_in, const int* in_sizes, int n_in,
                              void* d_out, int out_size, void* d_ws, size_t ws_size,
                              hipStream_t stream) {
    const float* x = (const float*)d_in[0];
    float* out = (float*)d_out;

    // 48 planes * 64 bands * 128 colsegs = 393216 threads
    int n_threads = (in_sizes[0] / (CENSUS_W * CENSUS_H)) * 64 * 128;
    int block = 256;
    int grid = (n_threads + block - 1) / block;

    census_kernel<<<grid, block, 0, stream>>>(x, out);
}